// Round 1
// baseline (323.780 us; speedup 1.0000x reference)
//
#include <hip/hip_runtime.h>

// EuclidConv + BatchNorm (training stats), fp32.
// out = BN(2*conv(x,w) + t1 + t2); t2 (per-channel const) cancels in BN -> skipped.
// t1 = conv(x^2, ones) computed in the same loop.

#define HW_    28
#define NPIX   784        // 28*28
#define HALO   30         // 28 + 2*pad
#define CI_    128
#define CO_    256
#define NB_    32
#define CI_T   8
#define CO_T   16
#define M_TOT  25088      // 32*784 elements per channel
#define SHIFT_ 1152.0f    // ~E[t1], conditioning shift for sumsq
#define BN_EPS 1e-5f

__global__ __launch_bounds__(256) void zero_stats(float* s) {
    int t = blockIdx.x * 256 + threadIdx.x;
    if (t < 2 * CO_) s[t] = 0.f;
}

__global__ __launch_bounds__(256) void conv_stats(
        const float* __restrict__ x, const float* __restrict__ w,
        float* __restrict__ y, float* __restrict__ stats) {
    const int n   = blockIdx.x;          // batch index
    const int co0 = blockIdx.y * CO_T;   // first output channel of this block
    const int tid = threadIdx.x;

    __shared__ float xs[CI_T][HALO * HALO];   // 28.8 KB: 8 input chans w/ halo
    __shared__ float wsh[CI_T][9][CO_T];      // 4.6 KB
    __shared__ float redS[4][CO_T], redS2[4][CO_T];

    float acc[4][CO_T];
    float t1[4] = {0.f, 0.f, 0.f, 0.f};
    #pragma unroll
    for (int k = 0; k < 4; ++k)
        #pragma unroll
        for (int c = 0; c < CO_T; ++c) acc[k][c] = 0.f;

    int base[4];
    #pragma unroll
    for (int k = 0; k < 4; ++k) {
        int p = tid + k * 256;
        if (p >= NPIX) p = NPIX - 1;              // clamp invalid slot (not stored)
        base[k] = (p / HW_) * HALO + (p % HW_);   // top-left of 3x3 window in halo tile
    }

    for (int ci0 = 0; ci0 < CI_; ci0 += CI_T) {
        __syncthreads();
        // stage x tile (with zero halo)
        for (int t = tid; t < CI_T * HALO * HALO; t += 256) {
            int ci = t / (HALO * HALO);
            int r  = t - ci * (HALO * HALO);
            int i  = r / HALO, j = r - i * HALO;
            int gi = i - 1, gj = j - 1;
            float v = 0.f;
            if (gi >= 0 && gi < HW_ && gj >= 0 && gj < HW_)
                v = x[((size_t)(n * CI_ + ci0 + ci) * HW_ + gi) * HW_ + gj];
            xs[ci][r] = v;
        }
        // stage w tile: wsh[ci][tap][co]
        for (int t = tid; t < CO_T * CI_T * 9; t += 256) {
            int co = t / (CI_T * 9);
            int r  = t - co * (CI_T * 9);
            int ci = r / 9, tap = r - ci * 9;
            wsh[ci][tap][co] = w[(size_t)(co0 + co) * (CI_ * 9) + (ci0 + ci) * 9 + tap];
        }
        __syncthreads();

        for (int ci = 0; ci < CI_T; ++ci) {
            #pragma unroll
            for (int kh = 0; kh < 3; ++kh)
            #pragma unroll
            for (int kw = 0; kw < 3; ++kw) {
                float xv[4];
                #pragma unroll
                for (int k = 0; k < 4; ++k) {
                    xv[k] = xs[ci][base[k] + kh * HALO + kw];
                    t1[k] = fmaf(xv[k], xv[k], t1[k]);   // ||patch||^2 accumulation
                }
                #pragma unroll
                for (int c = 0; c < CO_T; ++c) {
                    float wv = wsh[ci][kh * 3 + kw][c];  // uniform (broadcast) read
                    #pragma unroll
                    for (int k = 0; k < 4; ++k)
                        acc[k][c] = fmaf(xv[k], wv, acc[k][c]);
                }
            }
        }
    }

    // store pre-BN y and accumulate per-channel shifted stats
    const int wave = tid >> 6, lane = tid & 63;
    #pragma unroll
    for (int c = 0; c < CO_T; ++c) {
        float s = 0.f, s2 = 0.f;
        #pragma unroll
        for (int k = 0; k < 4; ++k) {
            int p = tid + k * 256;
            if (p < NPIX) {
                float yv = fmaf(2.f, acc[k][c], t1[k]);
                y[(size_t)(n * CO_ + co0 + c) * NPIX + p] = yv;
                float d = yv - SHIFT_;
                s += d;
                s2 = fmaf(d, d, s2);
            }
        }
        #pragma unroll
        for (int off = 32; off; off >>= 1) {
            s  += __shfl_down(s, off);
            s2 += __shfl_down(s2, off);
        }
        if (lane == 0) { redS[wave][c] = s; redS2[wave][c] = s2; }
    }
    __syncthreads();
    if (tid < 2 * CO_T) {
        int c     = tid & (CO_T - 1);
        int which = tid >> 4;
        float v = which ? (redS2[0][c] + redS2[1][c] + redS2[2][c] + redS2[3][c])
                        : (redS [0][c] + redS [1][c] + redS [2][c] + redS [3][c]);
        atomicAdd(&stats[which * CO_ + co0 + c], v);
    }
}

__global__ __launch_bounds__(256) void bn_apply(
        float* __restrict__ y, const float* __restrict__ stats,
        const float* __restrict__ gamma, const float* __restrict__ beta) {
    const int TOTAL4 = NB_ * CO_ * NPIX / 4;   // 1605632
    int i4 = blockIdx.x * 256 + threadIdx.x;
    if (i4 >= TOTAL4) return;
    int c = (i4 / (NPIX / 4)) & (CO_ - 1);
    float s    = stats[c];
    float s2   = stats[CO_ + c];
    const float invM = 1.0f / (float)M_TOT;
    float ms   = s * invM;                       // mean of shifted y
    float var  = fmaf(-ms, ms, s2 * invM);       // biased variance
    float mean = SHIFT_ + ms;
    float scale = rsqrtf(var + BN_EPS) * gamma[c];
    float bias  = beta[c] - mean * scale;
    float4 v = ((const float4*)y)[i4];
    v.x = fmaf(v.x, scale, bias);
    v.y = fmaf(v.y, scale, bias);
    v.z = fmaf(v.z, scale, bias);
    v.w = fmaf(v.w, scale, bias);
    ((float4*)y)[i4] = v;
}

extern "C" void kernel_launch(void* const* d_in, const int* in_sizes, int n_in,
                              void* d_out, int out_size, void* d_ws, size_t ws_size,
                              hipStream_t stream) {
    const float* x     = (const float*)d_in[0];
    const float* w     = (const float*)d_in[1];
    const float* gamma = (const float*)d_in[2];
    const float* beta  = (const float*)d_in[3];
    float* y     = (float*)d_out;
    float* stats = (float*)d_ws;   // [2][256] shifted sum / sumsq

    zero_stats<<<2, 256, 0, stream>>>(stats);
    conv_stats<<<dim3(NB_, CO_ / CO_T), 256, 0, stream>>>(x, w, y, stats);
    bn_apply<<<(NB_ * CO_ * NPIX / 4 + 255) / 256, 256, 0, stream>>>(y, stats, gamma, beta);
}

// Round 2
// 76.390 us; speedup vs baseline: 4.2385x; 4.2385x over previous
//
#include <hip/hip_runtime.h>

// EuclidConv + BatchNorm (training stats), fp32 in/out.
// y = 2*conv(x,w) + t1 (+t2, cancels in BN).  Conv via bf16 MFMA implicit GEMM:
//   M = 32*784 = 25088 pixels, N = 256 channels, K = 9 taps * 128 ci = 1152.
// t1 = conv(x^2, ones) kept in fp32 (separable: per-pixel ci-sum, then 3x3 box).

typedef short     bf16x8 __attribute__((ext_vector_type(8)));
typedef float     f32x4  __attribute__((ext_vector_type(4)));

#define NPIX   784
#define CI_    128
#define CO_    256
#define NB_    32
#define M_     25088
#define SHIFT_ 1152.0f
#define BN_EPS 1e-5f
#define M_TOT  25088

// ---- workspace layout (bytes) ----
// xp   : [32][30][30][128] bf16 = 7,372,800   (zero-padded NHWC)
// s    : [32][30][30] f32       =   115,200   (padded per-pixel sum of x^2)
// stats: [2][256] f32           =     2,048
// t1   : [25088] f32            =   100,352
// wp   : [36][16][4][16][8] bf16=   589,824   (MFMA B layout)
#define S_OFF   7372800
#define ST_OFF  7488000
#define T1_OFF  7490048
#define WP_OFF  7590400
#define ZERO_F4 468128            // (ST_OFF + 2048) / 16

__device__ __forceinline__ unsigned short f2bf(float f) {
    unsigned int u = __float_as_uint(f);
    unsigned int r = (u + 0x7FFFu + ((u >> 16) & 1u)) >> 16;
    return (unsigned short)r;
}

__device__ __forceinline__ void gload_lds16(const void* gsrc, void* ldst) {
    __builtin_amdgcn_global_load_lds(
        (const __attribute__((address_space(1))) void*)gsrc,
        (__attribute__((address_space(3))) void*)ldst, 16, 0, 0);
}

__global__ __launch_bounds__(256) void init_ws(float* ws) {
    int i = blockIdx.x * 256 + threadIdx.x;
    if (i < ZERO_F4) ((f32x4*)ws)[i] = (f32x4){0.f, 0.f, 0.f, 0.f};
}

// ---- pack x: NCHW f32 -> padded NHWC bf16, plus s = sum_ci x^2 (padded) ----
__global__ __launch_bounds__(256) void pack_x(const float* __restrict__ x,
                                              unsigned short* __restrict__ xp,
                                              float* __restrict__ s) {
    const int n = blockIdx.x / 28, h = blockIdx.x % 28, tid = threadIdx.x;
    __shared__ float xs[128][29];       // +1 pad: conflict-free column reads
    __shared__ float part[8][28];

    #pragma unroll
    for (int i = 0; i < 14; ++i) {
        int e = tid + i * 256;          // 3584 = 128ci * 28w
        int ci = e / 28, w = e - ci * 28;
        xs[ci][w] = x[(size_t)(n * 128 + ci) * 784 + h * 28 + w];
    }
    __syncthreads();
    // transpose-write xp[n][h+1][w+1][ci]
    #pragma unroll
    for (int i = 0; i < 14; ++i) {
        int e = tid + i * 256;
        int w = e >> 7, ci = e & 127;
        xp[((size_t)(n * 30 + h + 1) * 30 + (w + 1)) * 128 + ci] = f2bf(xs[ci][w]);
    }
    // s reduction
    if (tid < 224) {
        int grp = tid / 28, w = tid - grp * 28;
        float a = 0.f;
        #pragma unroll
        for (int ci = grp * 16; ci < grp * 16 + 16; ++ci) a = fmaf(xs[ci][w], xs[ci][w], a);
        part[grp][w] = a;
    }
    __syncthreads();
    if (tid < 28) {
        float a = 0.f;
        #pragma unroll
        for (int g = 0; g < 8; ++g) a += part[g][tid];
        s[n * 900 + (h + 1) * 30 + (tid + 1)] = a;
    }
}

// ---- pack w: [co][ci][3][3] f32 -> wp[kblk][ng][kb][cc][k8] bf16 ----
__global__ __launch_bounds__(256) void pack_w(const float* __restrict__ w,
                                              unsigned short* __restrict__ wp) {
    int o = blockIdx.x * 256 + threadIdx.x;      // < 294912
    int k8   = o & 7;
    int cc   = (o >> 3) & 15;
    int kb   = (o >> 7) & 3;
    int ng   = (o >> 9) & 15;
    int kblk = o >> 13;                          // 0..35
    int tap  = kblk >> 2;
    int ci   = (kblk & 3) * 32 + kb * 8 + k8;
    int co   = ng * 16 + cc;
    wp[o] = f2bf(w[(size_t)(co * 128 + ci) * 9 + tap]);
}

// ---- t1 = 3x3 box sum of padded s ----
__global__ __launch_bounds__(256) void t1k(const float* __restrict__ s,
                                           float* __restrict__ t1) {
    int g = blockIdx.x * 256 + threadIdx.x;
    if (g >= M_) return;
    int n = g / 784, p = g - n * 784;
    int h = p / 28, w = p - h * 28;
    const float* sb = s + n * 900 + h * 30 + w;
    t1[g] = (sb[0] + sb[1] + sb[2]) + (sb[30] + sb[31] + sb[32]) + (sb[60] + sb[61] + sb[62]);
}

// ---- MFMA implicit-GEMM conv: BM=128, BN=128, BK=64, 4 waves (2x2 of 64x64) ----
__global__ __launch_bounds__(256, 2) void econv_mfma(
        const unsigned short* __restrict__ xp, const unsigned short* __restrict__ wp,
        const float* __restrict__ t1, float* __restrict__ y, float* __restrict__ stats) {
    const int tid = threadIdx.x;
    const int gblock = blockIdx.x * 128;   // pixel-row base
    const int nblock = blockIdx.y * 128;   // channel base
    const int ng0 = nblock >> 4;

    __shared__ unsigned short As[128 * 64];          // 16KB, [row][slot] 16B chunks
    __shared__ unsigned short Bs[2 * 8 * 4 * 16 * 8];// 16KB, [q][ngl][kb][cc][8]
    __shared__ float t1s[128];

    // per-thread A-staging geometry: thread stages chunks c = tid + i*256
    // c -> row r = c>>3 (r0 + 32i), slot j = tid&7; content = source chunk j^(r&7)
    int rowoff[4];
    {
        int r0 = tid >> 3;
        #pragma unroll
        for (int i = 0; i < 4; ++i) {
            int g = gblock + r0 + i * 32;
            int n = g / 784, p = g - n * 784;
            int h = p / 28, wc = p - h * 28;
            rowoff[i] = (n * 30 + h) * 30 + wc;
        }
    }
    const int sig8 = (((tid & 7) ^ ((tid >> 3) & 7)) << 3);  // swizzled ci sub-offset

    if (tid < 128) t1s[tid] = t1[gblock + tid];

    f32x4 acc[4][4];
    #pragma unroll
    for (int a_ = 0; a_ < 4; ++a_)
        #pragma unroll
        for (int b_ = 0; b_ < 4; ++b_) acc[a_][b_] = (f32x4){0.f, 0.f, 0.f, 0.f};

    const int lane = tid & 63;
    const int wm = (tid >> 6) >> 1, wn = (tid >> 6) & 1;
    const int l15 = lane & 15, l16 = lane >> 4;

    for (int tap = 0; tap < 9; ++tap) {
        const int tapoff = (tap / 3) * 30 + (tap % 3);
        for (int half = 0; half < 2; ++half) {
            __syncthreads();
            // stage A[128][64] bf16 via global_load_lds, source pre-swizzled
            {
                const unsigned short* xpt = xp + half * 64 + sig8;
                #pragma unroll
                for (int i = 0; i < 4; ++i)
                    gload_lds16(xpt + (size_t)(rowoff[i] + tapoff) * 128,
                                &As[(tid + i * 256) * 8]);
            }
            // stage B: 2 k-blocks of 32, n-range [nblock, nblock+128): linear copy
            {
                const int kb0 = tap * 4 + half * 2;
                #pragma unroll
                for (int i = 0; i < 4; ++i) {
                    int c = tid + i * 256;                 // LDS chunk 0..1023
                    int q = c >> 9, ngl = (c >> 6) & 7, rest = c & 63;
                    int srcc = ((kb0 + q) * 16 + ng0 + ngl) * 64 + rest;
                    gload_lds16(wp + (size_t)srcc * 8, &Bs[c * 8]);
                }
            }
            __syncthreads();
            // compute: 2 k-blocks of 32
            #pragma unroll
            for (int q = 0; q < 2; ++q) {
                bf16x8 aF[4], bF[4];
                #pragma unroll
                for (int fm = 0; fm < 4; ++fm) {
                    int r = wm * 64 + fm * 16 + l15;
                    int kc = q * 4 + l16;
                    int j = kc ^ (r & 7);
                    aF[fm] = *(const bf16x8*)&As[(r * 8 + j) * 8];
                }
                #pragma unroll
                for (int fn = 0; fn < 4; ++fn) {
                    int c = q * 512 + (wn * 4 + fn) * 64 + l16 * 16 + l15;
                    bF[fn] = *(const bf16x8*)&Bs[c * 8];
                }
                #pragma unroll
                for (int fm = 0; fm < 4; ++fm)
                    #pragma unroll
                    for (int fn = 0; fn < 4; ++fn)
                        acc[fm][fn] = __builtin_amdgcn_mfma_f32_16x16x32_bf16(
                            aF[fm], bF[fn], acc[fm][fn], 0, 0, 0);
            }
        }
    }

    // epilogue: y = 2*acc + t1, shifted stats -> atomics
    float sSum[4] = {0.f, 0.f, 0.f, 0.f}, sSq[4] = {0.f, 0.f, 0.f, 0.f};
    #pragma unroll
    for (int fm = 0; fm < 4; ++fm) {
        #pragma unroll
        for (int j = 0; j < 4; ++j) {
            int r = wm * 64 + fm * 16 + l16 * 4 + j;
            int g = gblock + r;
            int n = g / 784, p = g - n * 784;
            float t1v = t1s[r];
            float* yb = y + (size_t)n * 200704 + p;
            #pragma unroll
            for (int fn = 0; fn < 4; ++fn) {
                int co = nblock + wn * 64 + fn * 16 + l15;
                float v = fmaf(2.f, acc[fm][fn][j], t1v);
                yb[co * 784] = v;
                float d = v - SHIFT_;
                sSum[fn] += d;
                sSq[fn] = fmaf(d, d, sSq[fn]);
            }
        }
    }
    #pragma unroll
    for (int fn = 0; fn < 4; ++fn) {
        float a = sSum[fn], b = sSq[fn];
        a += __shfl_xor(a, 16); a += __shfl_xor(a, 32);
        b += __shfl_xor(b, 16); b += __shfl_xor(b, 32);
        if (l16 == 0) {
            int co = nblock + wn * 64 + fn * 16 + l15;
            atomicAdd(&stats[co], a);
            atomicAdd(&stats[256 + co], b);
        }
    }
}

__global__ __launch_bounds__(256) void bn_apply(
        float* __restrict__ y, const float* __restrict__ stats,
        const float* __restrict__ gamma, const float* __restrict__ beta) {
    const int TOTAL4 = NB_ * CO_ * NPIX / 4;
    int i4 = blockIdx.x * 256 + threadIdx.x;
    if (i4 >= TOTAL4) return;
    int c = (i4 / (NPIX / 4)) & (CO_ - 1);
    float su  = stats[c];
    float s2  = stats[CO_ + c];
    const float invM = 1.0f / (float)M_TOT;
    float ms   = su * invM;
    float var  = fmaf(-ms, ms, s2 * invM);
    float mean = SHIFT_ + ms;
    float scale = rsqrtf(var + BN_EPS) * gamma[c];
    float bias  = beta[c] - mean * scale;
    f32x4 v = ((const f32x4*)y)[i4];
    v.x = fmaf(v.x, scale, bias);
    v.y = fmaf(v.y, scale, bias);
    v.z = fmaf(v.z, scale, bias);
    v.w = fmaf(v.w, scale, bias);
    ((f32x4*)y)[i4] = v;
}

extern "C" void kernel_launch(void* const* d_in, const int* in_sizes, int n_in,
                              void* d_out, int out_size, void* d_ws, size_t ws_size,
                              hipStream_t stream) {
    const float* x     = (const float*)d_in[0];
    const float* w     = (const float*)d_in[1];
    const float* gamma = (const float*)d_in[2];
    const float* beta  = (const float*)d_in[3];
    float* y = (float*)d_out;

    char* ws = (char*)d_ws;
    unsigned short* xp    = (unsigned short*)(ws);
    float*          s     = (float*)(ws + S_OFF);
    float*          stats = (float*)(ws + ST_OFF);
    float*          t1    = (float*)(ws + T1_OFF);
    unsigned short* wp    = (unsigned short*)(ws + WP_OFF);

    init_ws<<<(ZERO_F4 + 255) / 256, 256, 0, stream>>>((float*)ws);
    pack_x<<<NB_ * 28, 256, 0, stream>>>(x, xp, s);
    pack_w<<<294912 / 256, 256, 0, stream>>>(w, wp);
    t1k<<<(M_ + 255) / 256, 256, 0, stream>>>(s, t1);
    econv_mfma<<<dim3(196, 2), 256, 0, stream>>>(xp, wp, t1, y, stats);
    bn_apply<<<(NB_ * CO_ * NPIX / 4 + 255) / 256, 256, 0, stream>>>(y, stats, gamma, beta);
}

// Round 4
// 69.580 us; speedup vs baseline: 4.6534x; 1.0979x over previous
//
#include <hip/hip_runtime.h>

// EuclidConv + BatchNorm (training stats), fp32 in/out.
// y = 2*conv(x,w) + t1 (+t2 cancels in BN).  bf16 MFMA implicit GEMM:
//   M=25088 pixels, N=256 chans, K=9 taps*128 ci.
// Round 4: round-2-verified components + balanced grid (BM128/BN64, 784 blocks)
// + 4 blocks/CU occupancy. Serial K-loop (no dbuf) — dbuf is round 5's delta.

typedef short  bf16x8 __attribute__((ext_vector_type(8)));
typedef float  f32x4  __attribute__((ext_vector_type(4)));

#define NPIX   784
#define CI_    128
#define CO_    256
#define NB_    32
#define M_     25088
#define SHIFT_ 1152.0f
#define BN_EPS 1e-5f
#define M_TOT  25088

// ws layout (bytes): xp [32][30][30][128] bf16 = 7,372,800 ; s [32][30][30] f32 ;
// stats [2][256] f32 ; wp [36][16][4][16][8] bf16 = 589,824 (round-2 layout)
#define S_OFF   7372800
#define ST_OFF  7488000
#define WP_OFF  7490048
#define ZERO_F4 468128            // (ST_OFF + 2048) / 16 : zeroes xp + s + stats

__device__ __forceinline__ unsigned short f2bf(float f) {
    unsigned int u = __float_as_uint(f);
    unsigned int r = (u + 0x7FFFu + ((u >> 16) & 1u)) >> 16;
    return (unsigned short)r;
}

__device__ __forceinline__ void gload_lds16(const void* gsrc, void* ldst) {
    __builtin_amdgcn_global_load_lds(
        (const __attribute__((address_space(1))) void*)gsrc,
        (__attribute__((address_space(3))) void*)ldst, 16, 0, 0);
}

__global__ __launch_bounds__(256) void init_ws(float* ws) {
    int i = blockIdx.x * 256 + threadIdx.x;
    if (i < ZERO_F4) ((f32x4*)ws)[i] = (f32x4){0.f, 0.f, 0.f, 0.f};
}

// ---- pack x: NCHW f32 -> padded NHWC bf16, plus s = sum_ci x^2 (round-2) ----
__global__ __launch_bounds__(256) void pack_x(const float* __restrict__ x,
                                              unsigned short* __restrict__ xp,
                                              float* __restrict__ s) {
    const int n = blockIdx.x / 28, h = blockIdx.x % 28, tid = threadIdx.x;
    __shared__ float xs[128][29];
    __shared__ float part[8][28];

    #pragma unroll
    for (int i = 0; i < 14; ++i) {
        int e = tid + i * 256;
        int ci = e / 28, w = e - ci * 28;
        xs[ci][w] = x[(size_t)(n * 128 + ci) * 784 + h * 28 + w];
    }
    __syncthreads();
    #pragma unroll
    for (int i = 0; i < 14; ++i) {
        int e = tid + i * 256;
        int w = e >> 7, ci = e & 127;
        xp[((size_t)(n * 30 + h + 1) * 30 + (w + 1)) * 128 + ci] = f2bf(xs[ci][w]);
    }
    if (tid < 224) {
        int grp = tid / 28, w = tid - grp * 28;
        float a = 0.f;
        #pragma unroll
        for (int ci = grp * 16; ci < grp * 16 + 16; ++ci) a = fmaf(xs[ci][w], xs[ci][w], a);
        part[grp][w] = a;
    }
    __syncthreads();
    if (tid < 28) {
        float a = 0.f;
        #pragma unroll
        for (int g = 0; g < 8; ++g) a += part[g][tid];
        s[n * 900 + (h + 1) * 30 + (tid + 1)] = a;
    }
}

// ---- pack w (round-2 verified): wp[kblk(36)][ng(16)][kb(4)][cc(16)][k8(8)] ----
__global__ __launch_bounds__(256) void pack_w(const float* __restrict__ w,
                                              unsigned short* __restrict__ wp) {
    int o = blockIdx.x * 256 + threadIdx.x;      // < 294912
    int k8   = o & 7;
    int cc   = (o >> 3) & 15;
    int kb   = (o >> 7) & 3;
    int ng   = (o >> 9) & 15;
    int kblk = o >> 13;                          // 0..35
    int tap  = kblk >> 2;
    int ci   = (kblk & 3) * 32 + kb * 8 + k8;
    int co   = ng * 16 + cc;
    wp[o] = f2bf(w[(size_t)(co * 128 + ci) * 9 + tap]);
}

// ---- MFMA implicit GEMM: BM=128, BN=64, 4 waves (2x2 of 64x32), serial loop ----
__global__ __launch_bounds__(256, 4) void econv(
        const unsigned short* __restrict__ xp, const unsigned short* __restrict__ wp,
        const float* __restrict__ s, float* __restrict__ y, float* __restrict__ stats) {
    __shared__ unsigned short As[8192];   // 16KB  [row(128)][slot(8)][8]
    __shared__ unsigned short Bs[4096];   // 8KB   [q(2)][ngl(4)][kb(4)][cc(16)][8]
    __shared__ float t1s[128];

    const int tid = threadIdx.x;
    // XCD-aware bijective swizzle (784 = 8*98)
    int bid = blockIdx.x;
    int swz = (bid & 7) * 98 + (bid >> 3);
    const int nb = swz & 3;
    const int mb = swz >> 2;
    const int gblock = mb * 128;
    const int nblock = nb * 64;
    const int ng0 = nb * 4;

    // t1 = 3x3 box of padded per-pixel sum of x^2 (same formula as round-2 t1k)
    if (tid < 128) {
        int g = gblock + tid; int n = g / 784, p = g - n * 784;
        int h = p / 28, wq = p - h * 28;
        const float* sb = s + n * 900 + h * 30 + wq;
        t1s[tid] = (sb[0] + sb[1] + sb[2]) + (sb[30] + sb[31] + sb[32]) + (sb[60] + sb[61] + sb[62]);
    }

    int rowoff[4];
    {
        int r0 = tid >> 3;
        #pragma unroll
        for (int i = 0; i < 4; ++i) {
            int g = gblock + r0 + i * 32;
            int n = g / 784, p = g - n * 784;
            int h = p / 28, wc = p - h * 28;
            rowoff[i] = (n * 30 + h) * 30 + wc;
        }
    }
    const int sig8 = (((tid & 7) ^ ((tid >> 3) & 7)) << 3);
    const int lane = tid & 63;
    const int wid  = tid >> 6;
    const int wm = wid >> 1, wn = wid & 1;
    const int l15 = lane & 15, l16 = lane >> 4;

    f32x4 acc[4][2];
    #pragma unroll
    for (int a_ = 0; a_ < 4; ++a_)
        #pragma unroll
        for (int b_ = 0; b_ < 2; ++b_) acc[a_][b_] = (f32x4){0.f, 0.f, 0.f, 0.f};

    for (int tap = 0; tap < 9; ++tap) {
        const int tapoff = (tap / 3) * 30 + (tap % 3);
        for (int half = 0; half < 2; ++half) {
            __syncthreads();
            // stage A[128][64] bf16, source pre-swizzled (round-2 verified)
            {
                const unsigned short* xpt = xp + half * 64 + sig8;
                #pragma unroll
                for (int i = 0; i < 4; ++i)
                    gload_lds16(xpt + (size_t)(rowoff[i] + tapoff) * 128,
                                &As[(tid + i * 256) * 8]);
            }
            // stage B: 2 k-blocks of 32, channels [nblock, nblock+64)
            {
                const int kb0 = tap * 4 + half * 2;
                #pragma unroll
                for (int i = 0; i < 2; ++i) {
                    int c = tid + i * 256;                 // 0..511
                    int q = c >> 8, ngl = (c >> 6) & 3, rest = c & 63;
                    int srcc = ((kb0 + q) * 16 + ng0 + ngl) * 64 + rest;
                    gload_lds16(wp + (size_t)srcc * 8, &Bs[c * 8]);
                }
            }
            __syncthreads();
            #pragma unroll
            for (int q = 0; q < 2; ++q) {
                bf16x8 aF[4], bF[2];
                #pragma unroll
                for (int fm = 0; fm < 4; ++fm) {
                    int r = wm * 64 + fm * 16 + l15;
                    int j = (q * 4 + l16) ^ (r & 7);
                    aF[fm] = *(const bf16x8*)&As[(r * 8 + j) * 8];
                }
                #pragma unroll
                for (int fn = 0; fn < 2; ++fn) {
                    int c = q * 256 + (wn * 2 + fn) * 64 + l16 * 16 + l15;
                    bF[fn] = *(const bf16x8*)&Bs[c * 8];
                }
                #pragma unroll
                for (int fm = 0; fm < 4; ++fm)
                    #pragma unroll
                    for (int fn = 0; fn < 2; ++fn)
                        acc[fm][fn] = __builtin_amdgcn_mfma_f32_16x16x32_bf16(
                            aF[fm], bF[fn], acc[fm][fn], 0, 0, 0);
            }
        }
    }

    // epilogue (round-2 verified style): y = 2*acc + t1; shifted stats -> atomics
    float sSum[2] = {0.f, 0.f}, sSq[2] = {0.f, 0.f};
    #pragma unroll
    for (int fm = 0; fm < 4; ++fm) {
        #pragma unroll
        for (int j = 0; j < 4; ++j) {
            int r = wm * 64 + fm * 16 + l16 * 4 + j;
            int g = gblock + r;
            int n = g / 784, p = g - n * 784;
            float t1v = t1s[r];
            float* yb = y + (size_t)n * 200704 + p;
            #pragma unroll
            for (int fn = 0; fn < 2; ++fn) {
                int co = nblock + wn * 32 + fn * 16 + l15;
                float v = fmaf(2.f, acc[fm][fn][j], t1v);
                yb[co * 784] = v;
                float d = v - SHIFT_;
                sSum[fn] += d;
                sSq[fn] = fmaf(d, d, sSq[fn]);
            }
        }
    }
    #pragma unroll
    for (int fn = 0; fn < 2; ++fn) {
        float a = sSum[fn], b2 = sSq[fn];
        a  += __shfl_xor(a, 16);  a  += __shfl_xor(a, 32);
        b2 += __shfl_xor(b2, 16); b2 += __shfl_xor(b2, 32);
        if (l16 == 0) {
            int co = nblock + wn * 32 + fn * 16 + l15;
            atomicAdd(&stats[co], a);
            atomicAdd(&stats[256 + co], b2);
        }
    }
}

__global__ __launch_bounds__(256) void bn_apply(
        float* __restrict__ y, const float* __restrict__ stats,
        const float* __restrict__ gamma, const float* __restrict__ beta) {
    const int TOTAL4 = NB_ * CO_ * NPIX / 4;
    int i4 = blockIdx.x * 256 + threadIdx.x;
    if (i4 >= TOTAL4) return;
    int c = (i4 / (NPIX / 4)) & (CO_ - 1);
    float su = stats[c];
    float s2 = stats[CO_ + c];
    const float invM = 1.0f / (float)M_TOT;
    float ms   = su * invM;
    float var  = fmaf(-ms, ms, s2 * invM);
    float mean = SHIFT_ + ms;
    float scale = rsqrtf(var + BN_EPS) * gamma[c];
    float bias  = beta[c] - mean * scale;
    f32x4 v = ((const f32x4*)y)[i4];
    v.x = fmaf(v.x, scale, bias);
    v.y = fmaf(v.y, scale, bias);
    v.z = fmaf(v.z, scale, bias);
    v.w = fmaf(v.w, scale, bias);
    ((f32x4*)y)[i4] = v;
}

extern "C" void kernel_launch(void* const* d_in, const int* in_sizes, int n_in,
                              void* d_out, int out_size, void* d_ws, size_t ws_size,
                              hipStream_t stream) {
    const float* x     = (const float*)d_in[0];
    const float* w     = (const float*)d_in[1];
    const float* gamma = (const float*)d_in[2];
    const float* beta  = (const float*)d_in[3];
    float* y = (float*)d_out;

    char* ws = (char*)d_ws;
    unsigned short* xp    = (unsigned short*)(ws);
    float*          s     = (float*)(ws + S_OFF);
    float*          stats = (float*)(ws + ST_OFF);
    unsigned short* wp    = (unsigned short*)(ws + WP_OFF);

    init_ws<<<(ZERO_F4 + 255) / 256, 256, 0, stream>>>((float*)ws);
    pack_x<<<NB_ * 28, 256, 0, stream>>>(x, xp, s);
    pack_w<<<1152, 256, 0, stream>>>(w, wp);
    econv<<<784, 256, 0, stream>>>(xp, wp, s, y, stats);
    bn_apply<<<(NB_ * CO_ * NPIX / 4 + 255) / 256, 256, 0, stream>>>(y, stats, gamma, beta);
}